// Round 5
// baseline (133.249 us; speedup 1.0000x reference)
//
#include <hip/hip_runtime.h>
#include <hip/hip_bf16.h>
#include <stdint.h>

typedef unsigned short u16;
typedef __attribute__((ext_vector_type(8))) short short8;
typedef __attribute__((ext_vector_type(4))) float f32x4;
typedef __attribute__((ext_vector_type(16))) float f32x16;

#define NDIM 256
#define SDIM 128
#define DDIM 64
#define HDIM 32
#define PDIM 64
#define EPS 1e-5f

__device__ __forceinline__ u16 f2bf(float f) {
  union { float f; uint32_t u; } v; v.f = f;
  uint32_t r = v.u + 0x7fffu + ((v.u >> 16) & 1u);   // RNE
  return (u16)(r >> 16);
}

// ---------------- K1: LN + dual projection via MFMA ----------------
// grid 512: block = (n = bid>>1, sh = bid&1 -> s in [sh*64, sh*64+64)).
// Stores a_t/b_t rows PRE-SWIZZLED: element k of row lands at byte position
// (k&64) | (((k>>3)&7) ^ (row&7))<<3 | (k&7), so k_fused's global_load_lds
// staging produces the swizzled LDS image directly.
__global__ __launch_bounds__(256, 4) void k_pre(
    const float* __restrict__ msa, const float* __restrict__ mask,
    const float* __restrict__ gamma, const float* __restrict__ beta,
    const float* __restrict__ Wa, const float* __restrict__ ba,
    const float* __restrict__ Wb, const float* __restrict__ bb,
    const float* __restrict__ Wo,
    u16* __restrict__ a_t, u16* __restrict__ b_t, u16* __restrict__ W_t)
{
  __shared__ u16 xs[64 * 64];        // [sl][slot*8] swizzled, 8KB: X_norm bf16
  __shared__ u16 wt[64 * 64];        // [c][slot*8]  swizzled, 8KB: W^T bf16
  __shared__ float psum[2][4][64];
  __shared__ float maskF[128];
  __shared__ float gbF[128];         // gamma | beta

  const int n = blockIdx.x >> 1, sh = blockIdx.x & 1;
  const int t = threadIdx.x, lane = t & 63, wv = t >> 6;
  const int l15 = lane & 15, quad = lane >> 4;
  const int sl = lane, part = wv;

  if (t < 64) gbF[t] = gamma[t];
  else if (t < 128) gbF[t] = beta[t - 64];
  else maskF[t - 128] = mask[(t - 128) * NDIM + n];

  const int s_row = sh * 64 + sl;
  float x[16];
  {
    const float* xr = msa + (s_row * NDIM + n) * DDIM + part * 16;
    float sum = 0.f, sq = 0.f;
    #pragma unroll
    for (int i = 0; i < 4; ++i) {
      const float4 q = ((const float4*)xr)[i];
      x[4*i] = q.x; x[4*i+1] = q.y; x[4*i+2] = q.z; x[4*i+3] = q.w;
      sum += q.x + q.y + q.z + q.w;
      sq += q.x*q.x + q.y*q.y + q.z*q.z + q.w*q.w;
    }
    psum[0][part][sl] = sum;
    psum[1][part][sl] = sq;
  }

  {
    const int c31 = sl & 31;
    const float* Wsel = (sl >> 5) ? Wb : Wa;
    float w[16];
    #pragma unroll
    for (int i = 0; i < 16; ++i) w[i] = Wsel[(part * 16 + i) * HDIM + c31];
    #pragma unroll
    for (int jj = 0; jj < 2; ++jj) {
      short8 v;
      #pragma unroll
      for (int k = 0; k < 8; ++k) v[k] = (short)f2bf(w[jj * 8 + k]);
      *(short8*)&wt[sl * 64 + (((part * 2 + jj) ^ (sl & 7)) << 3)] = v;
    }
  }
  __syncthreads();

  {
    const float s0 = psum[0][0][sl] + psum[0][1][sl] + psum[0][2][sl] + psum[0][3][sl];
    const float s1 = psum[1][0][sl] + psum[1][1][sl] + psum[1][2][sl] + psum[1][3][sl];
    const float mu = s0 * (1.f / 64.f);
    const float var = s1 * (1.f / 64.f) - mu * mu;
    const float rs = rsqrtf(var + EPS);
    #pragma unroll
    for (int jj = 0; jj < 2; ++jj) {
      short8 v;
      #pragma unroll
      for (int k = 0; k < 8; ++k) {
        const int d = part * 16 + jj * 8 + k;
        v[k] = (short)f2bf((x[jj * 8 + k] - mu) * rs * gbF[d] + gbF[64 + d]);
      }
      *(short8*)&xs[sl * 64 + (((part * 2 + jj) ^ (sl & 7)) << 3)] = v;
    }
  }
  float dsum = 0.f;
  for (int ss = 0; ss < 128; ++ss) dsum += maskF[ss];
  const float dinv = 1.f / fmaxf(dsum, 1.f);
  __syncthreads();

  const f32x4 fz = {0.f, 0.f, 0.f, 0.f};
  f32x4 acc[4];
  #pragma unroll
  for (int nt = 0; nt < 4; ++nt) acc[nt] = fz;
  short8 af[2];
  #pragma unroll
  for (int ks = 0; ks < 2; ++ks)
    af[ks] = *(const short8*)&wt[(wv * 16 + l15) * 64 + (((ks * 4 + quad) ^ (l15 & 7)) << 3)];
  #pragma unroll
  for (int nt = 0; nt < 4; ++nt)
    #pragma unroll
    for (int ks = 0; ks < 2; ++ks) {
      const short8 bf = *(const short8*)&xs[(nt * 16 + l15) * 64 + (((ks * 4 + quad) ^ (l15 & 7)) << 3)];
      acc[nt] = __builtin_amdgcn_mfma_f32_16x16x32_bf16(af[ks], bf, acc[nt], 0, 0, 0);
    }

  const float* bsel = (wv < 2) ? ba : bb;
  float bias_r[4];
  #pragma unroll
  for (int r = 0; r < 4; ++r) bias_r[r] = bsel[(wv & 1) * 16 + quad * 4 + r];
  u16* dstbase = ((wv < 2) ? a_t : b_t) + n * 4096;
  #pragma unroll
  for (int nt = 0; nt < 4; ++nt) {
    const int s = sh * 64 + nt * 16 + l15;
    const float mval = maskF[s];
    const float scale = (wv < 2) ? mval * dinv : mval;
    #pragma unroll
    for (int r = 0; r < 4; ++r) {
      const int c31 = (wv & 1) * 16 + quad * 4 + r;
      // pre-swizzled position within the 128-element row (row&7 == c31&7)
      const int pos = (s & 64) | ((((s >> 3) & 7) ^ (c31 & 7)) << 3) | (s & 7);
      dstbase[c31 * 128 + pos] = f2bf((acc[nt][r] + bias_r[r]) * scale);
    }
  }

  if (blockIdx.x < 256) {
    const int f = blockIdx.x * 256 + t;
    const int p = f >> 10, hk = f & 1023;
    W_t[f] = f2bf(Wo[hk * 64 + p]);
  }
}

// ---------------- K2: fused outer-product GEMM + Wo contraction ----------------
// grid (64 jT, 32 iT) x 512 thr (8 waves). Stage A: G-tile 256ih x 128jk over
// K=128 (2 chunks), staging via global_load_lds from pre-swizzled a_t/b_t
// (no ds_writes, no VGPR round-trip). Wave grid 4(wm ih-quarter) x 2(wn jk-half),
// swapped operands D[m=jk][n=ih] -> packed b64 dump into swizzled Gs (64KB).
// Stage B: mfma_32x32x16, wave = (kq K-quarter, ph p-half): A[m = all 32 rij],
// W_t read exactly once per block; f32 exchange in LDS; 512-thread reduce+store.
__global__ __launch_bounds__(512, 4) void k_fused(
    const u16* __restrict__ a_t, const u16* __restrict__ b_t,
    const u16* __restrict__ W_t, const float* __restrict__ bo,
    float* __restrict__ out)
{
  __shared__ char smem[65536];
  u16* As = (u16*)smem;              // [256][64] per chunk (rows pre-swizzled)
  u16* Bs = (u16*)(smem + 32768);    // [128][64]
  u16* Gs = (u16*)smem;              // [32 rij][1024 hk] swizzled (after stage A)
  float* red = (float*)smem;         // [4 kq][32 rij][68] (after stage B)

  const int tid = threadIdx.x, lane = tid & 63, wv = tid >> 6;   // 8 waves
  const int l15 = lane & 15, quad = lane >> 4;
  const int wm = wv >> 1, wn = wv & 1;
  const int jT = blockIdx.x, iT = blockIdx.y;

  const u16* gA = a_t + iT * 256 * SDIM;
  const u16* gB = b_t + jT * 128 * SDIM;

  const f32x4 fz = {0.f, 0.f, 0.f, 0.f};
  f32x4 acc[4][4];                   // [jt][it]
  #pragma unroll
  for (int jt = 0; jt < 4; ++jt)
    #pragma unroll
    for (int it = 0; it < 4; ++it) acc[jt][it] = fz;

  const int sub8 = lane >> 3, g16 = lane & 7;

  for (int ch = 0; ch < 2; ++ch) {
    __syncthreads();
    #pragma unroll
    for (int i = 0; i < 4; ++i) {                // As: 256 rows, 8 rows/instr
      const int rbase = wv * 32 + i * 8;
      __builtin_amdgcn_global_load_lds(
          (const __attribute__((address_space(1))) void*)&gA[(rbase + sub8) * SDIM + ch * 64 + g16 * 8],
          (__attribute__((address_space(3))) void*)&As[rbase * 64], 16, 0, 0);
    }
    #pragma unroll
    for (int i = 0; i < 2; ++i) {                // Bs: 128 rows
      const int rbase = wv * 16 + i * 8;
      __builtin_amdgcn_global_load_lds(
          (const __attribute__((address_space(1))) void*)&gB[(rbase + sub8) * SDIM + ch * 64 + g16 * 8],
          (__attribute__((address_space(3))) void*)&Bs[rbase * 64], 16, 0, 0);
    }
    __syncthreads();
    #pragma unroll
    for (int ks = 0; ks < 2; ++ks) {
      const int g = ks * 4 + quad;
      short8 opA[4], opB[4];
      #pragma unroll
      for (int jt = 0; jt < 4; ++jt) {
        const int row = wn * 64 + jt * 16 + l15;
        opA[jt] = *(const short8*)&Bs[row * 64 + ((g ^ (row & 7)) << 3)];
      }
      #pragma unroll
      for (int it = 0; it < 4; ++it) {
        const int row = wm * 64 + it * 16 + l15;
        opB[it] = *(const short8*)&As[row * 64 + ((g ^ (row & 7)) << 3)];
      }
      #pragma unroll
      for (int jt = 0; jt < 4; ++jt)
        #pragma unroll
        for (int it = 0; it < 4; ++it)
          acc[jt][it] = __builtin_amdgcn_mfma_f32_16x16x32_bf16(opA[jt], opB[it], acc[jt][it], 0, 0, 0);
    }
  }
  __syncthreads();

  // Gs dump: D[m=jk (quad*4+r)][n=ih (l15)]; 4 regs = 4 consecutive hk -> b64.
  #pragma unroll
  for (int jt = 0; jt < 4; ++jt)
    #pragma unroll
    for (int it = 0; it < 4; ++it) {
      const int rij = (wm * 2 + (it >> 1)) * 4 + wn * 2 + (jt >> 1);
      const int ih31 = (it & 1) * 16 + l15;
      const int hk = ih31 * 32 + (jt & 1) * 16 + quad * 4;
      const int g4 = hk >> 2;
      const int g4s = g4 ^ ((g4 >> 4) & 6) ^ ((rij & 7) << 1);
      __hip_bfloat162 lo = __float22bfloat162_rn(float2{acc[jt][it][0], acc[jt][it][1]});
      __hip_bfloat162 hi = __float22bfloat162_rn(float2{acc[jt][it][2], acc[jt][it][3]});
      union { __hip_bfloat162 h[2]; uint2 u; } pk; pk.h[0] = lo; pk.h[1] = hi;
      *(uint2*)&Gs[rij * 1024 + (g4s << 2)] = pk.u;
    }
  __syncthreads();

  // Stage B: mfma_32x32x16. wave = (kq = wv>>1 K-quarter of 256 hk, ph = wv&1).
  // A[m=rij=lane&31][k=(lane>>5)*8+j] from Gs; B[k][n=p=lane&31] from W_t.
  const int kq = wv >> 1, ph = wv & 1;
  const int l31 = lane & 31, kh = lane >> 5;
  f32x16 bacc;
  #pragma unroll
  for (int r = 0; r < 16; ++r) bacc[r] = 0.f;
  const u16* wrow = W_t + (ph * 32 + l31) * 1024 + kq * 256 + kh * 8;
  const u16* grow = Gs + l31 * 1024;
  #pragma unroll
  for (int st = 0; st < 16; ++st) {
    const int g4e = kq * 64 + st * 4 + kh * 2;
    const int pos = g4e ^ ((g4e >> 4) & 6) ^ ((l31 & 7) << 1);
    const short8 ga = *(const short8*)&grow[pos << 2];
    const short8 wb = *(const short8*)&wrow[st * 16];
    bacc = __builtin_amdgcn_mfma_f32_32x32x16_bf16(ga, wb, bacc, 0, 0, 0);
  }
  __syncthreads();   // Gs reads done; reuse smem for exchange

  // D layout 32x32: col = lane&31 = p_local, row = (r&3)+8*(r>>2)+4*kh = rij
  #pragma unroll
  for (int r = 0; r < 16; ++r) {
    const int m = (r & 3) + 8 * (r >> 2) + 4 * kh;
    red[(kq * 32 + m) * 68 + ph * 32 + l31] = bacc[r];
  }
  __syncthreads();

  // reduce over 4 kq partials + bias + store (thread t -> rij = t>>4, 4 p)
  const int orow = tid >> 4, pq = (tid & 15) * 4;
  f32x4 s = fz;
  #pragma unroll
  for (int q = 0; q < 4; ++q)
    s += *(const f32x4*)&red[(q * 32 + orow) * 68 + pq];
  const float4 bo4 = ((const float4*)bo)[tid & 15];
  const int iG = iT * 8 + (orow >> 2), jG = jT * 4 + (orow & 3);
  float4 o;
  o.x = s[0] + bo4.x; o.y = s[1] + bo4.y; o.z = s[2] + bo4.z; o.w = s[3] + bo4.w;
  *(float4*)&out[(iG * NDIM + jG) * PDIM + pq] = o;
}

extern "C" void kernel_launch(void* const* d_in, const int* in_sizes, int n_in,
                              void* d_out, int out_size, void* d_ws, size_t ws_size,
                              hipStream_t stream) {
  const float* msa   = (const float*)d_in[0];
  const float* mask  = (const float*)d_in[1];
  const float* gamma = (const float*)d_in[2];
  const float* beta  = (const float*)d_in[3];
  const float* Wa    = (const float*)d_in[4];
  const float* ba    = (const float*)d_in[5];
  const float* Wb    = (const float*)d_in[6];
  const float* bb    = (const float*)d_in[7];
  const float* Wo    = (const float*)d_in[8];
  const float* bo    = (const float*)d_in[9];

  char* ws = (char*)d_ws;
  u16* a_t = (u16*)ws;                       // 2 MB: [8192 ih][128 s] bf16 (rows pre-swizzled)
  u16* b_t = (u16*)(ws + (2u << 20));        // 2 MB: [8192 jk][128 s] bf16 (rows pre-swizzled)
  u16* W_t = (u16*)(ws + (4u << 20));        // 128 KB: [64 p][1024 hk] bf16

  k_pre<<<dim3(512), dim3(256), 0, stream>>>(msa, mask, gamma, beta,
                                             Wa, ba, Wb, bb, Wo, a_t, b_t, W_t);
  k_fused<<<dim3(64, 32), dim3(512), 0, stream>>>(a_t, b_t, W_t, bo, (float*)d_out);
}

// Round 6
// 122.091 us; speedup vs baseline: 1.0914x; 1.0914x over previous
//
#include <hip/hip_runtime.h>
#include <hip/hip_bf16.h>
#include <stdint.h>

typedef unsigned short u16;
typedef __attribute__((ext_vector_type(8))) short short8;
typedef __attribute__((ext_vector_type(4))) float f32x4;

#define NDIM 256
#define SDIM 128
#define DDIM 64
#define HDIM 32
#define PDIM 64
#define EPS 1e-5f

__device__ __forceinline__ u16 f2bf(float f) {
  union { float f; uint32_t u; } v; v.f = f;
  uint32_t r = v.u + 0x7fffu + ((v.u >> 16) & 1u);   // RNE
  return (u16)(r >> 16);
}

// ---------------- K1: LN + dual projection via MFMA ----------------
// grid 512: block = (n = bid>>1, sh = bid&1). 256 thr = 4 waves.
// LN: thread = (row sl2 = wv*16 + lane>>2, d-slice part = lane&3) -> 4 lanes
// share one 64B msa line (coalesced groups). a_t/b_t rows stored PRE-SWIZZLED:
// element s of row c lands at (s&64) | (((s>>3)&7)^(c&7))<<3 | (s&7).
__global__ __launch_bounds__(256, 4) void k_pre(
    const float* __restrict__ msa, const float* __restrict__ mask,
    const float* __restrict__ gamma, const float* __restrict__ beta,
    const float* __restrict__ Wa, const float* __restrict__ ba,
    const float* __restrict__ Wb, const float* __restrict__ bb,
    const float* __restrict__ Wo,
    u16* __restrict__ a_t, u16* __restrict__ b_t, u16* __restrict__ W_t)
{
  __shared__ u16 xs[64 * 64];        // [s][slot*8] swizzled, 8KB: X_norm bf16
  __shared__ u16 wt[64 * 64];        // [c][slot*8] swizzled, 8KB: W^T bf16
  __shared__ float psum[2][4][64];
  __shared__ float maskF[128];
  __shared__ float gbF[128];         // gamma | beta

  const int n = blockIdx.x >> 1, sh = blockIdx.x & 1;
  const int t = threadIdx.x, lane = t & 63, wv = t >> 6;
  const int l15 = lane & 15, quad = lane >> 4;

  if (t < 64) gbF[t] = gamma[t];
  else if (t < 128) gbF[t] = beta[t - 64];
  else maskF[t - 128] = mask[(t - 128) * NDIM + n];

  // LN partials: row sl2, d-slice part (4 lanes per 64B line -> coalesced)
  const int sl2 = wv * 16 + (lane >> 2);
  const int part = lane & 3;
  float x[16];
  {
    const float* xr = msa + ((sh * 64 + sl2) * NDIM + n) * DDIM + part * 16;
    float sum = 0.f, sq = 0.f;
    #pragma unroll
    for (int i = 0; i < 4; ++i) {
      const float4 q = ((const float4*)xr)[i];
      x[4*i] = q.x; x[4*i+1] = q.y; x[4*i+2] = q.z; x[4*i+3] = q.w;
      sum += q.x + q.y + q.z + q.w;
      sq += q.x*q.x + q.y*q.y + q.z*q.z + q.w*q.w;
    }
    psum[0][part][sl2] = sum;
    psum[1][part][sl2] = sq;
  }

  // W^T: col c = lane (c<32 -> Wa, else Wb), d-slice wv*16..+16
  {
    const int c31 = lane & 31;
    const float* Wsel = (lane >> 5) ? Wb : Wa;
    float w[16];
    #pragma unroll
    for (int i = 0; i < 16; ++i) w[i] = Wsel[(wv * 16 + i) * HDIM + c31];
    #pragma unroll
    for (int jj = 0; jj < 2; ++jj) {
      short8 v;
      #pragma unroll
      for (int k = 0; k < 8; ++k) v[k] = (short)f2bf(w[jj * 8 + k]);
      *(short8*)&wt[lane * 64 + (((wv * 2 + jj) ^ (lane & 7)) << 3)] = v;
    }
  }
  __syncthreads();

  // finish LN for (sl2, part)
  {
    const float s0 = psum[0][0][sl2] + psum[0][1][sl2] + psum[0][2][sl2] + psum[0][3][sl2];
    const float s1 = psum[1][0][sl2] + psum[1][1][sl2] + psum[1][2][sl2] + psum[1][3][sl2];
    const float mu = s0 * (1.f / 64.f);
    const float var = s1 * (1.f / 64.f) - mu * mu;
    const float rs = rsqrtf(var + EPS);
    #pragma unroll
    for (int jj = 0; jj < 2; ++jj) {
      short8 v;
      #pragma unroll
      for (int k = 0; k < 8; ++k) {
        const int d = part * 16 + jj * 8 + k;
        v[k] = (short)f2bf((x[jj * 8 + k] - mu) * rs * gbF[d] + gbF[64 + d]);
      }
      *(short8*)&xs[sl2 * 64 + (((part * 2 + jj) ^ (sl2 & 7)) << 3)] = v;
    }
  }
  // denom via shuffle reduction
  float m2 = maskF[lane] + maskF[64 + lane];
  #pragma unroll
  for (int m = 32; m; m >>= 1) m2 += __shfl_xor(m2, m, 64);
  const float dinv = 1.f / fmaxf(m2, 1.f);
  __syncthreads();

  // projection MFMA: D[m=c][n=s], wave wv owns c-tile [wv*16, +16)
  const f32x4 fz = {0.f, 0.f, 0.f, 0.f};
  f32x4 acc[4];
  #pragma unroll
  for (int nt = 0; nt < 4; ++nt) acc[nt] = fz;
  short8 af[2];
  #pragma unroll
  for (int ks = 0; ks < 2; ++ks)
    af[ks] = *(const short8*)&wt[(wv * 16 + l15) * 64 + (((ks * 4 + quad) ^ (l15 & 7)) << 3)];
  #pragma unroll
  for (int nt = 0; nt < 4; ++nt)
    #pragma unroll
    for (int ks = 0; ks < 2; ++ks) {
      const short8 bf = *(const short8*)&xs[(nt * 16 + l15) * 64 + (((ks * 4 + quad) ^ (l15 & 7)) << 3)];
      acc[nt] = __builtin_amdgcn_mfma_f32_16x16x32_bf16(af[ks], bf, acc[nt], 0, 0, 0);
    }

  // epilogue: +bias, scale, pre-swizzled store
  const float* bsel = (wv < 2) ? ba : bb;
  float bias_r[4];
  #pragma unroll
  for (int r = 0; r < 4; ++r) bias_r[r] = bsel[(wv & 1) * 16 + quad * 4 + r];
  u16* dstbase = ((wv < 2) ? a_t : b_t) + n * 4096;
  #pragma unroll
  for (int nt = 0; nt < 4; ++nt) {
    const int s = sh * 64 + nt * 16 + l15;
    const float mval = maskF[s];
    const float scale = (wv < 2) ? mval * dinv : mval;
    #pragma unroll
    for (int r = 0; r < 4; ++r) {
      const int c31 = (wv & 1) * 16 + quad * 4 + r;
      const int pos = (s & 64) | ((((s >> 3) & 7) ^ (c31 & 7)) << 3) | (s & 7);
      dstbase[c31 * 128 + pos] = f2bf((acc[nt][r] + bias_r[r]) * scale);
    }
  }

  // W_t2[hk>>3][p][hk&7] = bf16(Wo[hk][p]) — coalesced stage-B loads
  if (blockIdx.x < 256) {
    const int f = blockIdx.x * 256 + t;        // f = hk*64 + p
    const int p = f & 63, hk = f >> 6;
    W_t[(hk >> 3) * 512 + p * 8 + (hk & 7)] = f2bf(Wo[f]);
  }
}

// ---------------- K2: fused outer-product GEMM + Wo contraction ----------------
// grid (32 jT, 32 iT) x 512 thr (8 waves: wi 0..3 ih-quarter, wj 0..1 jk-half).
// Stage A: G-tile 256ih x 256jk over K=128 (2 chunks of 64), global_load_lds
// staging from pre-swizzled a_t/b_t; 8x4 register blocking acc[jt 8][it 4]
// (swapped operands: D[m=jk][n=ih] -> regs = 4 consecutive k -> b64 dump).
// Then 2 passes of 32 rij: dump (waves wi>>1==pass) -> stage B (wave=(kq,ph),
// W slice exclusive, coalesced W_t2 reads) -> red exchange -> reduce+store.
__global__ __launch_bounds__(512, 2) void k_fused(
    const u16* __restrict__ a_t, const u16* __restrict__ b_t,
    const u16* __restrict__ W_t, const float* __restrict__ bo,
    float* __restrict__ out)
{
  __shared__ char smem[65536];
  u16* As = (u16*)smem;              // [256 ih][64 k] per chunk, 32KB
  u16* Bs = (u16*)(smem + 32768);    // [256 jk][64 k] per chunk, 32KB
  u16* Gs = (u16*)smem;              // [32 rij][1024 hk] swizzled, 64KB (per pass)
  float* red = (float*)smem;         // [4 kq][32 rij][pitch 68] f32 (after stage B)

  const int tid = threadIdx.x, lane = tid & 63, wv = tid >> 6;   // 8 waves
  const int l15 = lane & 15, quad = lane >> 4;
  const int wi = wv >> 1, wj = wv & 1;
  const int jT = blockIdx.x, iT = blockIdx.y;

  const u16* gA = a_t + iT * 256 * SDIM;
  const u16* gB = b_t + jT * 256 * SDIM;

  const f32x4 fz = {0.f, 0.f, 0.f, 0.f};
  f32x4 acc[8][4];                   // [jt][it]
  #pragma unroll
  for (int jt = 0; jt < 8; ++jt)
    #pragma unroll
    for (int it = 0; it < 4; ++it) acc[jt][it] = fz;

  const int sub8 = lane >> 3, g16 = lane & 7;

  for (int ch = 0; ch < 2; ++ch) {
    __syncthreads();
    #pragma unroll
    for (int i = 0; i < 4; ++i) {                // As: 256 rows, 8 rows/instr
      const int rbase = wv * 32 + i * 8;
      __builtin_amdgcn_global_load_lds(
          (const __attribute__((address_space(1))) void*)&gA[(rbase + sub8) * SDIM + ch * 64 + g16 * 8],
          (__attribute__((address_space(3))) void*)&As[rbase * 64], 16, 0, 0);
    }
    #pragma unroll
    for (int i = 0; i < 4; ++i) {                // Bs: 256 rows
      const int rbase = wv * 32 + i * 8;
      __builtin_amdgcn_global_load_lds(
          (const __attribute__((address_space(1))) void*)&gB[(rbase + sub8) * SDIM + ch * 64 + g16 * 8],
          (__attribute__((address_space(3))) void*)&Bs[rbase * 64], 16, 0, 0);
    }
    __syncthreads();
    #pragma unroll
    for (int ks = 0; ks < 2; ++ks) {
      const int g = ks * 4 + quad;
      short8 afr[4], bfr[8];
      #pragma unroll
      for (int it = 0; it < 4; ++it) {
        const int row = wi * 64 + it * 16 + l15;
        afr[it] = *(const short8*)&As[row * 64 + ((g ^ (row & 7)) << 3)];
      }
      #pragma unroll
      for (int jt = 0; jt < 8; ++jt) {
        const int row = wj * 128 + jt * 16 + l15;
        bfr[jt] = *(const short8*)&Bs[row * 64 + ((g ^ (row & 7)) << 3)];
      }
      #pragma unroll
      for (int jt = 0; jt < 8; ++jt)
        #pragma unroll
        for (int it = 0; it < 4; ++it)
          acc[jt][it] = __builtin_amdgcn_mfma_f32_16x16x32_bf16(bfr[jt], afr[it], acc[jt][it], 0, 0, 0);
    }
  }

  #pragma unroll 1
  for (int pass = 0; pass < 2; ++pass) {
    __syncthreads();   // Gs region free (stage-A reads / prev pass done)
    if ((wi >> 1) == pass) {
      // dump this pass's 32 rij. D[m=jk (quad*4+r)][n=ih (l15)].
      #pragma unroll
      for (int jt = 0; jt < 8; ++jt)
        #pragma unroll
        for (int it = 0; it < 4; ++it) {
          const int rij = ((wi & 1) * 2 + (it >> 1)) * 8 + wj * 4 + (jt >> 1);
          const int h = (it & 1) * 16 + l15;
          const int hk = h * 32 + (jt & 1) * 16 + quad * 4;
          const int g4 = hk >> 2;
          const int g4s = g4 ^ ((g4 >> 4) & 6) ^ ((rij & 7) << 1);
          __hip_bfloat162 lo = __float22bfloat162_rn(float2{acc[jt][it][0], acc[jt][it][1]});
          __hip_bfloat162 hi = __float22bfloat162_rn(float2{acc[jt][it][2], acc[jt][it][3]});
          union { __hip_bfloat162 h2[2]; uint2 u; } pk; pk.h2[0] = lo; pk.h2[1] = hi;
          *(uint2*)&Gs[rij * 1024 + (g4s << 2)] = pk.u;
        }
    }
    __syncthreads();

    // stage B: wave = (kq = wv>>1, ph = wv&1); M=32(2 mt), N=32(2 nt), K=256(8 ks)
    const int kq = wv >> 1, ph = wv & 1;
    f32x4 ob[2][2];
    #pragma unroll
    for (int mt = 0; mt < 2; ++mt)
      #pragma unroll
      for (int nt = 0; nt < 2; ++nt) ob[mt][nt] = fz;
    #pragma unroll 2
    for (int ks = 0; ks < 8; ++ks) {
      const int kb = kq * 32 + ks * 4 + quad;       // hk>>3
      const int g4e = kb * 2;
      const int go = (g4e ^ ((g4e >> 4) & 6) ^ ((l15 & 7) << 1)) << 2;
      short8 ga[2], wf[2];
      #pragma unroll
      for (int mt = 0; mt < 2; ++mt)
        ga[mt] = *(const short8*)&Gs[(mt * 16 + l15) * 1024 + go];
      #pragma unroll
      for (int nt = 0; nt < 2; ++nt)
        wf[nt] = *(const short8*)&W_t[kb * 512 + (ph * 32 + nt * 16 + l15) * 8];
      #pragma unroll
      for (int mt = 0; mt < 2; ++mt)
        #pragma unroll
        for (int nt = 0; nt < 2; ++nt)
          ob[mt][nt] = __builtin_amdgcn_mfma_f32_16x16x32_bf16(ga[mt], wf[nt], ob[mt][nt], 0, 0, 0);
    }
    __syncthreads();   // all Gs reads done -> red may overwrite

    #pragma unroll
    for (int mt = 0; mt < 2; ++mt)
      #pragma unroll
      for (int nt = 0; nt < 2; ++nt)
        #pragma unroll
        for (int r = 0; r < 4; ++r) {
          const int rij = mt * 16 + quad * 4 + r;
          const int p = ph * 32 + nt * 16 + l15;
          red[(kq * 32 + rij) * 68 + p] = ob[mt][nt][r];
        }
    __syncthreads();

    // reduce 4 kq partials + bias + store: thread t -> (rij = t>>4, 4 p)
    {
      const int rij = tid >> 4, pq = (tid & 15) * 4;
      f32x4 s = fz;
      #pragma unroll
      for (int q = 0; q < 4; ++q)
        s += *(const f32x4*)&red[(q * 32 + rij) * 68 + pq];
      const float4 bo4 = ((const float4*)bo)[tid & 15];
      const int iG = iT * 8 + pass * 4 + (rij >> 3);
      const int jG = jT * 8 + (rij & 7);
      float4 o;
      o.x = s[0] + bo4.x; o.y = s[1] + bo4.y; o.z = s[2] + bo4.z; o.w = s[3] + bo4.w;
      *(float4*)&out[(iG * NDIM + jG) * PDIM + pq] = o;
    }
  }
}

extern "C" void kernel_launch(void* const* d_in, const int* in_sizes, int n_in,
                              void* d_out, int out_size, void* d_ws, size_t ws_size,
                              hipStream_t stream) {
  const float* msa   = (const float*)d_in[0];
  const float* mask  = (const float*)d_in[1];
  const float* gamma = (const float*)d_in[2];
  const float* beta  = (const float*)d_in[3];
  const float* Wa    = (const float*)d_in[4];
  const float* ba    = (const float*)d_in[5];
  const float* Wb    = (const float*)d_in[6];
  const float* bb    = (const float*)d_in[7];
  const float* Wo    = (const float*)d_in[8];
  const float* bo    = (const float*)d_in[9];

  char* ws = (char*)d_ws;
  u16* a_t = (u16*)ws;                       // 2 MB: [8192 ih][128 s] bf16 (pre-swizzled rows)
  u16* b_t = (u16*)(ws + (2u << 20));        // 2 MB: [8192 jk][128 s] bf16 (pre-swizzled rows)
  u16* W_t = (u16*)(ws + (4u << 20));        // 128 KB: [hk/8][p][hk%8] bf16

  k_pre<<<dim3(512), dim3(256), 0, stream>>>(msa, mask, gamma, beta,
                                             Wa, ba, Wb, bb, Wo, a_t, b_t, W_t);
  k_fused<<<dim3(32, 32), dim3(512), 0, stream>>>(a_t, b_t, W_t, bo, (float*)d_out);
}